// Round 5
// baseline (129.121 us; speedup 1.0000x reference)
//
#include <hip/hip_runtime.h>
#include <hip/hip_bf16.h>
#include <math.h>

#define NRES   4096
#define NBATCH 1024
#define NIN    128
#define NOUT   64
// K layout: [0,4096) x/W_res bf16 | [4096,4224) hiP*hiW | [4224,4352) hiP*loW
//           [4352,4480) loP*hiW | [4480,4544) hiT*hiWo | [4544,4608) hiT*loWo | [4608,4672) loT*hiWo
#define KT     4672
#define KQ     (KT / 4)
#define TILES  73          // K-tiles of 64; split 19/18/18/18 over blockIdx.z

typedef __bf16 bf16x8 __attribute__((ext_vector_type(8)));
typedef __bf16 bf16x4 __attribute__((ext_vector_type(4)));
typedef float  f32x4  __attribute__((ext_vector_type(4)));

__device__ __forceinline__ float lo_part(float f) {
    return f - (float)(__bf16)f;
}

__device__ __forceinline__ void gload_lds16(const void* g, void* l) {
    __builtin_amdgcn_global_load_lds(
        (const __attribute__((address_space(1))) unsigned int*)g,
        (__attribute__((address_space(3))) unsigned int*)l, 16, 0, 0);
}

__global__ __launch_bounds__(256) void pack_A4(
    const float* __restrict__ x, const float* __restrict__ passed,
    const float* __restrict__ lastOut, const float* __restrict__ lastPred,
    const float* __restrict__ prob, const float* __restrict__ rand_num,
    __bf16* __restrict__ Abuf)
{
    unsigned id = blockIdx.x * 256u + threadIdx.x;
    if (id >= (unsigned)NBATCH * KQ) return;
    unsigned b = id / KQ;
    unsigned k = (id - b * KQ) * 4u;
    f32x4 v;
    if (k < 4096u) {
        v = *(const f32x4*)(x + (size_t)b * NRES + k);
    } else if (k < 4224u) {
        v = *(const f32x4*)(passed + b * NIN + (k - 4096u));            // hi
    } else if (k < 4352u) {
        v = *(const f32x4*)(passed + b * NIN + (k - 4224u));            // hi (pairs loW)
    } else if (k < 4480u) {
        f32x4 f = *(const f32x4*)(passed + b * NIN + (k - 4352u));      // lo
#pragma unroll
        for (int e = 0; e < 4; ++e) v[e] = lo_part(f[e]);
    } else {
        const float* src = (rand_num[0] < prob[0]) ? lastOut : lastPred;
#pragma unroll
        for (int e = 0; e < 4; ++e) {
            unsigned kk = k + e;
            unsigned j; bool want_lo;
            if (kk < 4544u)      { j = kk - 4480u; want_lo = false; }
            else if (kk < 4608u) { j = kk - 4544u; want_lo = false; }
            else                 { j = kk - 4608u; want_lo = true;  }
            float f = src[j * NBATCH + b];
            v[e] = want_lo ? lo_part(f) : f;
        }
    }
    bf16x4 o;
#pragma unroll
    for (int e = 0; e < 4; ++e) o[e] = (__bf16)v[e];
    *(bf16x4*)(Abuf + (size_t)id * 4u) = o;
}

__global__ __launch_bounds__(256) void pack_B4(
    const float* __restrict__ W_res, const float* __restrict__ W_in,
    const float* __restrict__ W_out, __bf16* __restrict__ Bbuf)
{
    unsigned id = blockIdx.x * 256u + threadIdx.x;
    if (id >= (unsigned)NRES * KQ) return;
    unsigned n = id / KQ;
    unsigned k = (id - n * KQ) * 4u;
    f32x4 v;
    if (k < 4096u) {
        v = *(const f32x4*)(W_res + (size_t)n * NRES + k);
    } else if (k < 4224u) {
        v = *(const f32x4*)(W_in + n * NIN + (k - 4096u));              // hi
    } else if (k < 4352u) {
        f32x4 f = *(const f32x4*)(W_in + n * NIN + (k - 4224u));        // lo (pairs hiP)
#pragma unroll
        for (int e = 0; e < 4; ++e) v[e] = lo_part(f[e]);
    } else if (k < 4480u) {
        v = *(const f32x4*)(W_in + n * NIN + (k - 4352u));              // hi (pairs loP)
    } else if (k < 4544u) {
        v = *(const f32x4*)(W_out + n * NOUT + (k - 4480u));            // hi
    } else if (k < 4608u) {
        f32x4 f = *(const f32x4*)(W_out + n * NOUT + (k - 4544u));      // lo
#pragma unroll
        for (int e = 0; e < 4; ++e) v[e] = lo_part(f[e]);
    } else {
        v = *(const f32x4*)(W_out + n * NOUT + (k - 4608u));            // hi
    }
    bf16x4 o;
#pragma unroll
    for (int e = 0; e < 4; ++e) o[e] = (__bf16)v[e];
    *(bf16x4*)(Bbuf + (size_t)id * 4u) = o;
}

__global__ __launch_bounds__(256) void zero_accum(float* __restrict__ a)
{
    size_t i = (size_t)blockIdx.x * 256u + threadIdx.x;   // 1,048,576 f32x4 units
    ((f32x4*)a)[i] = (f32x4){0.f, 0.f, 0.f, 0.f};
}

// 256x256 tile, 8 waves (2M x 4N), per-wave 128x64, BK=64, split-K over z.
// 8-phase schedule (4 phases/K-tile): each phase = {ds_read subtile, stage one
// 16KB chunk of tile t+1, counted vmcnt, barrier, setprio+16 MFMA, barrier}.
// Chunks in consumption order c0(A-half0'),c2(B-half0'),c3(B-half1'),c1(A-half1')
// with interleaved row groups so phase j needs only chunks <= j of tile t.
__global__ __launch_bounds__(512, 1) void gemm_kernel(
    const __bf16* __restrict__ Abuf, const __bf16* __restrict__ Bbuf,
    float* __restrict__ accum)
{
    __shared__ __align__(16) char smem[2][65536];   // [buf][A 32KB | B 32KB]

    const int t  = threadIdx.x;
    const int l  = t & 63;
    const int w  = t >> 6;     // 0..7
    const int wm = w >> 2;     // 0..1 : 128-row slab
    const int wn = w & 3;      // 0..3 : 64-col slab
    const int bn = blockIdx.x, bm = blockIdx.y, bz = blockIdx.z;
    const int t0 = bz * 18 + (bz ? 1 : 0);   // first K-tile of this split
    const int nt = 18 + (bz == 0);           // 19,18,18,18

    f32x4 acc[8][4] = {};

    // ---- stage precompute: chunk c, unit j: 2 x 16B per thread per chunk.
    // Source column XOR-swizzled so swizzled ds_reads see correct data (rule #21);
    // LDS dest stays linear per wave (gload_lds requirement).
    unsigned goff[4][2];
    int ldst[4][2];
#pragma unroll
    for (int c = 0; c < 4; ++c) {
#pragma unroll
        for (int j = 0; j < 2; ++j) {
            int ui = j * 512 + t;
            int lr = ui >> 3;
            int cb = (ui & 7) << 4;
            int rc;
            if (c == 0)      rc = (lr & 63) + ((lr >> 6) << 7);        // A rows 0..63,128..191
            else if (c == 1) rc = 64 + (lr & 63) + ((lr >> 6) << 7);   // A rows 64..127,192..255
            else if (c == 2) rc = (lr & 31) + ((lr >> 5) << 6);        // B cols {0..31}+64k
            else             rc = 32 + (lr & 31) + ((lr >> 5) << 6);   // B cols {32..63}+64k
            int cs = cb ^ ((rc & 7) << 4);
            if (c < 2) {
                goff[c][j] = (unsigned)((bm * 256 + rc) * KT + (cs >> 1));
                ldst[c][j] = rc * 128 + cb;
            } else {
                goff[c][j] = (unsigned)((bn * 256 + rc) * KT + (cs >> 1));
                ldst[c][j] = 32768 + rc * 128 + cb;
            }
        }
    }

    // ---- fragment read byte-offsets (kk=1 is ^64: bit6 lives below row*128)
    int offA[8], offB[4];
#pragma unroll
    for (int m = 0; m < 8; ++m) {
        int row = wm * 128 + m * 16 + (l & 15);
        offA[m] = row * 128 + ((((l >> 4) << 4)) ^ ((row & 7) << 4));
    }
#pragma unroll
    for (int n = 0; n < 4; ++n) {
        int col = wn * 64 + n * 16 + (l & 15);
        offB[n] = 32768 + col * 128 + ((((l >> 4) << 4)) ^ ((col & 7) << 4));
    }

    bf16x8 af[4][2], bf[4][2];

#define BAR() do { asm volatile("" ::: "memory");                        \
                   __builtin_amdgcn_s_barrier();                         \
                   asm volatile("" ::: "memory"); } while (0)

#define STAGEC(c, nxt, k0n)                                              \
    do {                                                                 \
        gload_lds16(((c) < 2 ? Abuf : Bbuf) + goff[c][0] + (k0n),        \
                    smem[nxt] + ldst[c][0]);                             \
        gload_lds16(((c) < 2 ? Abuf : Bbuf) + goff[c][1] + (k0n),        \
                    smem[nxt] + ldst[c][1]);                             \
    } while (0)

#define LDA(q)                                                           \
    do {                                                                 \
        _Pragma("unroll")                                                \
        for (int m2 = 0; m2 < 4; ++m2) {                                 \
            af[m2][0] = *(const bf16x8*)(S + offA[(q)*4 + m2]);          \
            af[m2][1] = *(const bf16x8*)(S + (offA[(q)*4 + m2] ^ 64));   \
        }                                                                \
    } while (0)

#define LDB(h)                                                           \
    do {                                                                 \
        _Pragma("unroll")                                                \
        for (int n3 = 0; n3 < 2; ++n3) {                                 \
            bf[(h)*2+n3][0] = *(const bf16x8*)(S + offB[(h)*2 + n3]);    \
            bf[(h)*2+n3][1] = *(const bf16x8*)(S + (offB[(h)*2+n3] ^ 64)); \
        }                                                                \
    } while (0)

#define MFMA16(qm, qn)                                                   \
    do {                                                                 \
        __builtin_amdgcn_s_setprio(1);                                   \
        _Pragma("unroll")                                                \
        for (int kk2 = 0; kk2 < 2; ++kk2)                                \
            _Pragma("unroll")                                            \
            for (int m2 = 0; m2 < 4; ++m2)                               \
                _Pragma("unroll")                                        \
                for (int n2 = 0; n2 < 2; ++n2)                           \
                    acc[(qm)*4+m2][(qn)*2+n2] =                          \
                        __builtin_amdgcn_mfma_f32_16x16x32_bf16(         \
                            af[m2][kk2], bf[(qn)*2+n2][kk2],             \
                            acc[(qm)*4+m2][(qn)*2+n2], 0, 0, 0);         \
        __builtin_amdgcn_s_setprio(0);                                   \
    } while (0)

    // Prologue: stage tile 0 in consumption order; wait c0,c2 (c3,c1 in flight).
    {
        const int k00 = t0 * 64;
        STAGEC(0, 0, k00); STAGEC(2, 0, k00); STAGEC(3, 0, k00); STAGEC(1, 0, k00);
        asm volatile("s_waitcnt vmcnt(4)" ::: "memory");
        BAR();
    }

    for (int tt = 0; tt < nt - 1; ++tt) {
        const char* S = smem[tt & 1];
        const int nxt = (tt & 1) ^ 1;
        const int k0n = (t0 + tt + 1) * 64;
        // Phase 0: quadrant (m0..3, n0..1); stage c0(t+1); guarantee c3(t)
        LDA(0); LDB(0);
        STAGEC(0, nxt, k0n);
        asm volatile("s_waitcnt vmcnt(4)" ::: "memory");
        BAR();
        MFMA16(0, 0);
        BAR();
        // Phase 1: (m0..3, n2..3); stage c2(t+1); guarantee c1(t)
        LDB(1);
        STAGEC(2, nxt, k0n);
        asm volatile("s_waitcnt vmcnt(4)" ::: "memory");
        BAR();
        MFMA16(0, 1);
        BAR();
        // Phase 2: (m4..7, n0..1); stage c3(t+1); no wait needed
        LDA(1);
        STAGEC(3, nxt, k0n);
        BAR();
        MFMA16(1, 0);
        BAR();
        // Phase 3: (m4..7, n2..3); stage c1(t+1); guarantee c0,c2(t+1)
        STAGEC(1, nxt, k0n);
        asm volatile("s_waitcnt vmcnt(4)" ::: "memory");
        BAR();
        MFMA16(1, 1);
        BAR();
    }
    {   // Tail tile (no staging): tighter counts
        const char* S = smem[(nt - 1) & 1];
        LDA(0); LDB(0);
        asm volatile("s_waitcnt vmcnt(2)" ::: "memory");
        BAR();
        MFMA16(0, 0);
        BAR();
        LDB(1);
        asm volatile("s_waitcnt vmcnt(0)" ::: "memory");
        BAR();
        MFMA16(0, 1);
        BAR();
        LDA(1);
        BAR();
        MFMA16(1, 0);
        BAR();
        MFMA16(1, 1);
    }

    // Split-K epilogue: atomic f32 accumulate.
    // C/D layout: col = lane&15, row = (lane>>4)*4 + reg  [m89/m91-verified]
    const int r0 = bm * 256 + wm * 128 + ((l >> 4) << 2);
    const int c0 = bn * 256 + wn * 64 + (l & 15);
#pragma unroll
    for (int m = 0; m < 8; ++m) {
#pragma unroll
        for (int i = 0; i < 4; ++i) {
            float* arow = accum + (size_t)(r0 + m * 16 + i) * NRES;
#pragma unroll
            for (int n = 0; n < 4; ++n)
                atomicAdd(arow + c0 + n * 16, acc[m][n][i]);
        }
    }
#undef BAR
#undef STAGEC
#undef LDA
#undef LDB
#undef MFMA16
}

__global__ __launch_bounds__(256) void epilogue_kernel(
    const float* __restrict__ accum, const float* __restrict__ xin,
    const float* __restrict__ Bin, float* __restrict__ out)
{
    size_t id = (size_t)blockIdx.x * 256u + threadIdx.x;   // 1,048,576 units
    size_t e  = id * 4;
    int c = (int)(e & (NRES - 1));
    f32x4 a = *(const f32x4*)(accum + e);
    f32x4 xv = *(const f32x4*)(xin + e);
    f32x4 bv = *(const f32x4*)(Bin + c);
    f32x4 o;
#pragma unroll
    for (int j = 0; j < 4; ++j)
        o[j] = 0.1f * xv[j] + 0.9f * tanhf(a[j] + bv[j]);
    *(f32x4*)(out + e) = o;
}

extern "C" void kernel_launch(void* const* d_in, const int* in_sizes, int n_in,
                              void* d_out, int out_size, void* d_ws, size_t ws_size,
                              hipStream_t stream) {
    (void)in_sizes; (void)n_in; (void)out_size; (void)ws_size;
    const float* passed     = (const float*)d_in[0];
    const float* lastOutput = (const float*)d_in[1];
    const float* lastPred   = (const float*)d_in[2];
    const float* x          = (const float*)d_in[3];
    const float* prob       = (const float*)d_in[4];
    const float* rand_num   = (const float*)d_in[5];
    const float* W_in       = (const float*)d_in[6];
    const float* W_res      = (const float*)d_in[7];
    const float* W_out      = (const float*)d_in[8];
    const float* B_in       = (const float*)d_in[9];
    float* out = (float*)d_out;

    __bf16* Abuf = (__bf16*)d_ws;                                    // 9,568,256 B
    __bf16* Bbuf = (__bf16*)((char*)d_ws + (size_t)NBATCH * KT * 2); // 38,273,024 B
    float*  accum = (float*)((char*)d_ws + (size_t)(NBATCH + NRES) * KT * 2); // 16,777,216 B

    zero_accum<<<4096, 256, 0, stream>>>(accum);
    pack_A4<<<(NBATCH * KQ) / 256, 256, 0, stream>>>(
        x, passed, lastOutput, lastPred, prob, rand_num, Abuf);
    pack_B4<<<(NRES * KQ) / 256, 256, 0, stream>>>(
        W_res, W_in, W_out, Bbuf);

    dim3 grid(NRES / 256, NBATCH / 256, 4);
    gemm_kernel<<<grid, 512, 0, stream>>>(Abuf, Bbuf, accum);

    epilogue_kernel<<<4096, 256, 0, stream>>>(accum, x, B_in, out);
}

// Round 6
// 86.071 us; speedup vs baseline: 1.5002x; 1.5002x over previous
//
#include <hip/hip_runtime.h>
#include <hip/hip_bf16.h>
#include <math.h>

#define NRES   4096
#define NBATCH 1024
#define NIN    128
#define NOUT   64
// K layout: [0,4096) x/W_res bf16 | [4096,4224) hiP*hiW | [4224,4352) hiP*loW
//           [4352,4480) loP*hiW | [4480,4544) hiT*hiWo | [4544,4608) hiT*loWo | [4608,4672) loT*hiWo
#define KT     4672
#define KQ     (KT / 4)
#define TILES  73
#define MN     ((size_t)NBATCH * NRES)

typedef __bf16 bf16x8 __attribute__((ext_vector_type(8)));
typedef __bf16 bf16x4 __attribute__((ext_vector_type(4)));
typedef float  f32x4  __attribute__((ext_vector_type(4)));

__device__ __forceinline__ float lo_part(float f) {
    return f - (float)(__bf16)f;
}

__device__ __forceinline__ void gload_lds16(const __bf16* g, __bf16* l) {
    __builtin_amdgcn_global_load_lds(
        (const __attribute__((address_space(1))) unsigned int*)g,
        (__attribute__((address_space(3))) unsigned int*)l, 16, 0, 0);
}

__global__ __launch_bounds__(256) void pack_A4(
    const float* __restrict__ x, const float* __restrict__ passed,
    const float* __restrict__ lastOut, const float* __restrict__ lastPred,
    const float* __restrict__ prob, const float* __restrict__ rand_num,
    __bf16* __restrict__ Abuf)
{
    unsigned id = blockIdx.x * 256u + threadIdx.x;
    if (id >= (unsigned)NBATCH * KQ) return;
    unsigned b = id / KQ;
    unsigned k = (id - b * KQ) * 4u;
    f32x4 v;
    if (k < 4096u) {
        v = *(const f32x4*)(x + (size_t)b * NRES + k);
    } else if (k < 4224u) {
        v = *(const f32x4*)(passed + b * NIN + (k - 4096u));            // hi
    } else if (k < 4352u) {
        v = *(const f32x4*)(passed + b * NIN + (k - 4224u));            // hi (pairs loW)
    } else if (k < 4480u) {
        f32x4 f = *(const f32x4*)(passed + b * NIN + (k - 4352u));      // lo
#pragma unroll
        for (int e = 0; e < 4; ++e) v[e] = lo_part(f[e]);
    } else {
        const float* src = (rand_num[0] < prob[0]) ? lastOut : lastPred;
#pragma unroll
        for (int e = 0; e < 4; ++e) {
            unsigned kk = k + e;
            unsigned j; bool want_lo;
            if (kk < 4544u)      { j = kk - 4480u; want_lo = false; }
            else if (kk < 4608u) { j = kk - 4544u; want_lo = false; }
            else                 { j = kk - 4608u; want_lo = true;  }
            float f = src[j * NBATCH + b];
            v[e] = want_lo ? lo_part(f) : f;
        }
    }
    bf16x4 o;
#pragma unroll
    for (int e = 0; e < 4; ++e) o[e] = (__bf16)v[e];
    *(bf16x4*)(Abuf + (size_t)id * 4u) = o;
}

__global__ __launch_bounds__(256) void pack_B4(
    const float* __restrict__ W_res, const float* __restrict__ W_in,
    const float* __restrict__ W_out, __bf16* __restrict__ Bbuf)
{
    unsigned id = blockIdx.x * 256u + threadIdx.x;
    if (id >= (unsigned)NRES * KQ) return;
    unsigned n = id / KQ;
    unsigned k = (id - n * KQ) * 4u;
    f32x4 v;
    if (k < 4096u) {
        v = *(const f32x4*)(W_res + (size_t)n * NRES + k);
    } else if (k < 4224u) {
        v = *(const f32x4*)(W_in + n * NIN + (k - 4096u));              // hi
    } else if (k < 4352u) {
        f32x4 f = *(const f32x4*)(W_in + n * NIN + (k - 4224u));        // lo (pairs hiP)
#pragma unroll
        for (int e = 0; e < 4; ++e) v[e] = lo_part(f[e]);
    } else if (k < 4480u) {
        v = *(const f32x4*)(W_in + n * NIN + (k - 4352u));              // hi (pairs loP)
    } else if (k < 4544u) {
        v = *(const f32x4*)(W_out + n * NOUT + (k - 4480u));            // hi
    } else if (k < 4608u) {
        f32x4 f = *(const f32x4*)(W_out + n * NOUT + (k - 4544u));      // lo
#pragma unroll
        for (int e = 0; e < 4; ++e) v[e] = lo_part(f[e]);
    } else {
        v = *(const f32x4*)(W_out + n * NOUT + (k - 4608u));            // hi
    }
    bf16x4 o;
#pragma unroll
    for (int e = 0; e < 4; ++e) o[e] = (__bf16)v[e];
    *(bf16x4*)(Bbuf + (size_t)id * 4u) = o;
}

// 256x256 tile, 8 waves (2Mx4N), wave-tile 128x64, BK=64, split-K over blockIdx.z.
// dbuf LDS 2x64KB. ALL staging for tile t+1 issues at phase 0 of tile t; ONE
// vmcnt(0) at phase 3 (max lead ~3.5 phases). 4 sub-phases x 16 MFMA + setprio.
// All LDS reads through direct __shared__ GEPs (ds_read, never flat).
// Split-K partials: plain f32 stores to part[z] (no atomics).
__global__ __launch_bounds__(512, 1) void gemm_kernel(
    const __bf16* __restrict__ Abuf, const __bf16* __restrict__ Bbuf,
    float* __restrict__ part, int split)
{
    __shared__ __align__(16) __bf16 SH[2][32768];   // [buf][A 16384 | B 16384] elems

    const int t  = threadIdx.x;
    const int l  = t & 63;
    const int w  = t >> 6;     // 0..7
    const int wm = w >> 2;     // 0..1 : 128-row slab
    const int wn = w & 3;      // 0..3 : 64-col slab
    const int bn = blockIdx.x, bm = blockIdx.y, bz = blockIdx.z;
    const int qs = TILES / split, rs = TILES % split;
    const int t0 = bz * qs + (bz < rs ? bz : rs);
    const int nt = qs + (bz < rs ? 1 : 0);

    f32x4 acc[8][4] = {};

    // ---- staging precompute: A 2048 16B-chunks (4/thread), B same.
    // LDS dest linear (gload_lds requirement); XOR swizzle on SOURCE column (rule #21).
    unsigned gA[4], gB[4];
    int lA[4], lB[4];
#pragma unroll
    for (int j = 0; j < 4; ++j) {
        int ca  = j * 512 + t;             // chunk 0..2047
        int row = ca >> 3;                 // 0..255
        int cb  = (ca & 7) << 4;           // byte-in-row
        int cs  = cb ^ ((row & 7) << 4);   // swizzled source byte
        gA[j] = (unsigned)((bm * 256 + row) * KT) + (cs >> 1);
        gB[j] = (unsigned)((bn * 256 + row) * KT) + (cs >> 1);
        lA[j] = ca * 8;                    // element index (16B = 8 elems)
        lB[j] = 16384 + ca * 8;
    }

#define STAGE_ALL(nxt, k0n)                                              \
    do {                                                                 \
        _Pragma("unroll")                                                \
        for (int j = 0; j < 4; ++j)                                      \
            gload_lds16(Abuf + gA[j] + (k0n), &SH[nxt][lA[j]]);          \
        _Pragma("unroll")                                                \
        for (int j = 0; j < 4; ++j)                                      \
            gload_lds16(Bbuf + gB[j] + (k0n), &SH[nxt][lB[j]]);          \
    } while (0)

    // ---- fragment read ELEMENT offsets (swizzled); kk=1 is ^32 elems (^64 bytes)
    int eA[8], eB[4];
#pragma unroll
    for (int m = 0; m < 8; ++m) {
        int row = wm * 128 + m * 16 + (l & 15);
        eA[m] = row * 64 + (((((l >> 4) << 4)) ^ ((row & 7) << 4)) >> 1);
    }
#pragma unroll
    for (int n = 0; n < 4; ++n) {
        int col = wn * 64 + n * 16 + (l & 15);
        eB[n] = 16384 + col * 64 + (((((l >> 4) << 4)) ^ ((col & 7) << 4)) >> 1);
    }

    bf16x8 af[4][2], bfr[4][2];

#define BAR() do { asm volatile("" ::: "memory");                        \
                   __builtin_amdgcn_s_barrier();                         \
                   asm volatile("" ::: "memory"); } while (0)

#define LDA(qd, buf)                                                     \
    do {                                                                 \
        _Pragma("unroll")                                                \
        for (int m2 = 0; m2 < 4; ++m2) {                                 \
            af[m2][0] = *(const bf16x8*)&SH[buf][eA[(qd)*4 + m2]];       \
            af[m2][1] = *(const bf16x8*)&SH[buf][eA[(qd)*4 + m2] ^ 32];  \
        }                                                                \
    } while (0)

#define LDB(h, buf)                                                      \
    do {                                                                 \
        _Pragma("unroll")                                                \
        for (int n3 = 0; n3 < 2; ++n3) {                                 \
            bfr[(h)*2+n3][0] = *(const bf16x8*)&SH[buf][eB[(h)*2 + n3]]; \
            bfr[(h)*2+n3][1] = *(const bf16x8*)&SH[buf][eB[(h)*2+n3] ^ 32]; \
        }                                                                \
    } while (0)

#define MFMA16(qm, qn)                                                   \
    do {                                                                 \
        __builtin_amdgcn_s_setprio(1);                                   \
        _Pragma("unroll")                                                \
        for (int kk2 = 0; kk2 < 2; ++kk2)                                \
            _Pragma("unroll")                                            \
            for (int m2 = 0; m2 < 4; ++m2)                               \
                _Pragma("unroll")                                        \
                for (int n2 = 0; n2 < 2; ++n2)                           \
                    acc[(qm)*4+m2][(qn)*2+n2] =                          \
                        __builtin_amdgcn_mfma_f32_16x16x32_bf16(         \
                            af[m2][kk2], bfr[(qn)*2+n2][kk2],            \
                            acc[(qm)*4+m2][(qn)*2+n2], 0, 0, 0);         \
        __builtin_amdgcn_s_setprio(0);                                   \
    } while (0)

    // Prologue: stage tile 0 into buf 0, drain, barrier.
    STAGE_ALL(0, t0 * 64);
    asm volatile("s_waitcnt vmcnt(0)" ::: "memory");
    BAR();

    for (int tt = 0; tt < nt; ++tt) {
        const int cur = tt & 1;
        const int nxt = cur ^ 1;
        const bool pf = (tt + 1 < nt);
        // Phase 0: issue ALL staging for t+1, then quadrant (m0..3, n0..1)
        if (pf) STAGE_ALL(nxt, (t0 + tt + 1) * 64);
        LDA(0, cur); LDB(0, cur);
        BAR();
        MFMA16(0, 0);
        BAR();
        // Phase 1: (m0..3, n2..3)
        LDB(1, cur);
        BAR();
        MFMA16(0, 1);
        BAR();
        // Phase 2: (m4..7, n0..1)
        LDA(1, cur);
        BAR();
        MFMA16(1, 0);
        BAR();
        // Phase 3: wait for tile t+1's loads (issued 3.5 phases ago), then (m4..7, n2..3)
        if (pf) asm volatile("s_waitcnt vmcnt(0)" ::: "memory");
        BAR();
        MFMA16(1, 1);
        // no trailing barrier: next phase-0 stage targets the buffer whose
        // reads all completed before the phase-2 post-barrier.
    }

    // Split-K partial store (plain f32, no atomics).
    // C/D layout: col = lane&15, row = (lane>>4)*4 + reg  [m89/m91-verified]
    float* pz = part + (size_t)bz * MN;
    const int r0 = bm * 256 + wm * 128 + ((l >> 4) << 2);
    const int c0 = bn * 256 + wn * 64 + (l & 15);
#pragma unroll
    for (int m = 0; m < 8; ++m) {
#pragma unroll
        for (int i = 0; i < 4; ++i) {
            float* prow = pz + (size_t)(r0 + m * 16 + i) * NRES;
#pragma unroll
            for (int n = 0; n < 4; ++n)
                prow[c0 + n * 16] = acc[m][n][i];
        }
    }
#undef STAGE_ALL
#undef BAR
#undef LDA
#undef LDB
#undef MFMA16
}

__global__ __launch_bounds__(256) void epilogue_kernel(
    const float* __restrict__ part, int split, const float* __restrict__ xin,
    const float* __restrict__ Bin, float* __restrict__ out)
{
    size_t id = (size_t)blockIdx.x * 256u + threadIdx.x;   // 1,048,576 units
    size_t e  = id * 4;
    int c = (int)(e & (NRES - 1));
    f32x4 s = *(const f32x4*)(part + e);
    for (int z = 1; z < split; ++z) {
        f32x4 p = *(const f32x4*)(part + (size_t)z * MN + e);
        s += p;
    }
    f32x4 xv = *(const f32x4*)(xin + e);
    f32x4 bv = *(const f32x4*)(Bin + c);
    f32x4 o;
#pragma unroll
    for (int j = 0; j < 4; ++j)
        o[j] = 0.1f * xv[j] + 0.9f * tanhf(s[j] + bv[j]);
    *(f32x4*)(out + e) = o;
}

extern "C" void kernel_launch(void* const* d_in, const int* in_sizes, int n_in,
                              void* d_out, int out_size, void* d_ws, size_t ws_size,
                              hipStream_t stream) {
    (void)in_sizes; (void)n_in; (void)out_size;
    const float* passed     = (const float*)d_in[0];
    const float* lastOutput = (const float*)d_in[1];
    const float* lastPred   = (const float*)d_in[2];
    const float* x          = (const float*)d_in[3];
    const float* prob       = (const float*)d_in[4];
    const float* rand_num   = (const float*)d_in[5];
    const float* W_in       = (const float*)d_in[6];
    const float* W_res      = (const float*)d_in[7];
    const float* W_out      = (const float*)d_in[8];
    const float* B_in       = (const float*)d_in[9];
    float* out = (float*)d_out;

    const size_t AB = (size_t)(NBATCH + NRES) * KT * 2;   // 47,841,280 B
    __bf16* Abuf = (__bf16*)d_ws;
    __bf16* Bbuf = (__bf16*)((char*)d_ws + (size_t)NBATCH * KT * 2);
    float*  part = (float*)((char*)d_ws + AB);

    // ws-guarded split-K factor (deterministic: ws_size fixed per session)
    int split = 1;
    if (ws_size >= AB + 4 * MN * sizeof(float))      split = 4;
    else if (ws_size >= AB + 2 * MN * sizeof(float)) split = 2;

    pack_A4<<<(NBATCH * KQ) / 256, 256, 0, stream>>>(
        x, passed, lastOutput, lastPred, prob, rand_num, Abuf);
    pack_B4<<<(NRES * KQ) / 256, 256, 0, stream>>>(
        W_res, W_in, W_out, Bbuf);

    dim3 grid(NRES / 256, NBATCH / 256, split);
    gemm_kernel<<<grid, 512, 0, stream>>>(Abuf, Bbuf, part, split);

    epilogue_kernel<<<4096, 256, 0, stream>>>(part, split, x, B_in, out);
}

// Round 7
// 84.068 us; speedup vs baseline: 1.5359x; 1.0238x over previous
//
#include <hip/hip_runtime.h>
#include <hip/hip_bf16.h>
#include <math.h>

#define NRES   4096
#define NBATCH 1024
#define NIN    128
#define NOUT   64
// K layout: [0,4096) x/W_res bf16 | [4096,4224) hiP*hiW | [4224,4352) hiP*loW
//           [4352,4480) loP*hiW | [4480,4544) hiT*hiWo | [4544,4608) hiT*loWo | [4608,4672) loT*hiWo
#define KT     4672
#define KQ     (KT / 4)
#define TILES  73
#define MN     ((size_t)NBATCH * NRES)

typedef __bf16 bf16x8 __attribute__((ext_vector_type(8)));
typedef __bf16 bf16x4 __attribute__((ext_vector_type(4)));
typedef float  f32x4  __attribute__((ext_vector_type(4)));

__device__ __forceinline__ float lo_part(float f) {
    return f - (float)(__bf16)f;
}

__device__ __forceinline__ void gload_lds16(const __bf16* g, __bf16* l) {
    __builtin_amdgcn_global_load_lds(
        (const __attribute__((address_space(1))) unsigned int*)g,
        (__attribute__((address_space(3))) unsigned int*)l, 16, 0, 0);
}

__global__ __launch_bounds__(256) void pack_A4(
    const float* __restrict__ x, const float* __restrict__ passed,
    const float* __restrict__ lastOut, const float* __restrict__ lastPred,
    const float* __restrict__ prob, const float* __restrict__ rand_num,
    __bf16* __restrict__ Abuf)
{
    unsigned id = blockIdx.x * 256u + threadIdx.x;
    if (id >= (unsigned)NBATCH * KQ) return;
    unsigned b = id / KQ;
    unsigned k = (id - b * KQ) * 4u;
    f32x4 v;
    if (k < 4096u) {
        v = *(const f32x4*)(x + (size_t)b * NRES + k);
    } else if (k < 4224u) {
        v = *(const f32x4*)(passed + b * NIN + (k - 4096u));            // hi
    } else if (k < 4352u) {
        v = *(const f32x4*)(passed + b * NIN + (k - 4224u));            // hi (pairs loW)
    } else if (k < 4480u) {
        f32x4 f = *(const f32x4*)(passed + b * NIN + (k - 4352u));      // lo
#pragma unroll
        for (int e = 0; e < 4; ++e) v[e] = lo_part(f[e]);
    } else {
        const float* src = (rand_num[0] < prob[0]) ? lastOut : lastPred;
#pragma unroll
        for (int e = 0; e < 4; ++e) {
            unsigned kk = k + e;
            unsigned j; bool want_lo;
            if (kk < 4544u)      { j = kk - 4480u; want_lo = false; }
            else if (kk < 4608u) { j = kk - 4544u; want_lo = false; }
            else                 { j = kk - 4608u; want_lo = true;  }
            float f = src[j * NBATCH + b];
            v[e] = want_lo ? lo_part(f) : f;
        }
    }
    bf16x4 o;
#pragma unroll
    for (int e = 0; e < 4; ++e) o[e] = (__bf16)v[e];
    *(bf16x4*)(Abuf + (size_t)id * 4u) = o;
}

__global__ __launch_bounds__(256) void pack_B4(
    const float* __restrict__ W_res, const float* __restrict__ W_in,
    const float* __restrict__ W_out, __bf16* __restrict__ Bbuf)
{
    unsigned id = blockIdx.x * 256u + threadIdx.x;
    if (id >= (unsigned)NRES * KQ) return;
    unsigned n = id / KQ;
    unsigned k = (id - n * KQ) * 4u;
    f32x4 v;
    if (k < 4096u) {
        v = *(const f32x4*)(W_res + (size_t)n * NRES + k);
    } else if (k < 4224u) {
        v = *(const f32x4*)(W_in + n * NIN + (k - 4096u));              // hi
    } else if (k < 4352u) {
        f32x4 f = *(const f32x4*)(W_in + n * NIN + (k - 4224u));        // lo (pairs hiP)
#pragma unroll
        for (int e = 0; e < 4; ++e) v[e] = lo_part(f[e]);
    } else if (k < 4480u) {
        v = *(const f32x4*)(W_in + n * NIN + (k - 4352u));              // hi (pairs loP)
    } else if (k < 4544u) {
        v = *(const f32x4*)(W_out + n * NOUT + (k - 4480u));            // hi
    } else if (k < 4608u) {
        f32x4 f = *(const f32x4*)(W_out + n * NOUT + (k - 4544u));      // lo
#pragma unroll
        for (int e = 0; e < 4; ++e) v[e] = lo_part(f[e]);
    } else {
        v = *(const f32x4*)(W_out + n * NOUT + (k - 4608u));            // hi
    }
    bf16x4 o;
#pragma unroll
    for (int e = 0; e < 4; ++e) o[e] = (__bf16)v[e];
    *(bf16x4*)(Bbuf + (size_t)id * 4u) = o;
}

// 256x256 tile, 8 waves (2Mx4N), wave-tile 128x64, BK=64, split-K over blockIdx.z.
// m201-style 4-phase schedule per K-tile: one 16KB chunk staged per phase in
// consumption order (c0,c2,c3,c1), counted vmcnt(4) at phases 0/1/3 (never 0
// in the main loop). Chunk consumed at phase P is vmcnt+barrier-covered in a
// phase <= P-1 (ds_read executes at issue time). dbuf LDS 2x64KB.
// All LDS reads via direct __shared__ GEPs (ds_read, never flat).
__global__ __launch_bounds__(512, 1) void gemm_kernel(
    const __bf16* __restrict__ Abuf, const __bf16* __restrict__ Bbuf,
    float* __restrict__ part, int split)
{
    __shared__ __align__(16) __bf16 SH[2][32768];   // [buf][A 16384 | B 16384] elems

    const int t  = threadIdx.x;
    const int l  = t & 63;
    const int w  = t >> 6;     // 0..7
    const int wm = w >> 2;     // 0..1 : 128-row slab
    const int wn = w & 3;      // 0..3 : 64-col slab
    const int bn = blockIdx.x, bm = blockIdx.y, bz = blockIdx.z;
    const int qs = TILES / split, rs = TILES % split;
    const int t0 = bz * qs + (bz < rs ? bz : rs);
    const int nt = qs + (bz < rs ? 1 : 0);

    f32x4 acc[8][4] = {};

    // ---- staging precompute: 4 chunks x (2 x 16B per thread).
    // c0: A rows {0-63,128-191} (feeds LDA(0)); c1: A rows {64-127,192-255} (LDA(1));
    // c2: B cols {0-31,+64k} (LDB(0));          c3: B cols {32-63,+64k} (LDB(1)).
    // LDS dest linear (gload_lds requirement); XOR swizzle on SOURCE column (rule #21).
    unsigned goff[4][2];
    int lE[4][2];
#pragma unroll
    for (int c = 0; c < 4; ++c) {
#pragma unroll
        for (int j = 0; j < 2; ++j) {
            int ui = j * 512 + t;              // unit 0..1023 within chunk
            int lr = ui >> 3;                  // 0..127
            int cb = (ui & 7) << 4;            // byte-in-row 0..112
            int rc;
            if (c == 0)      rc = (lr & 63) + ((lr >> 6) << 7);
            else if (c == 1) rc = 64 + (lr & 63) + ((lr >> 6) << 7);
            else if (c == 2) rc = (lr & 31) + ((lr >> 5) << 6);
            else             rc = 32 + (lr & 31) + ((lr >> 5) << 6);
            int cs = cb ^ ((rc & 7) << 4);     // swizzled source byte
            if (c < 2) {
                goff[c][j] = (unsigned)((bm * 256 + rc) * KT) + (cs >> 1);
                lE[c][j]   = rc * 64 + (cb >> 1);
            } else {
                goff[c][j] = (unsigned)((bn * 256 + rc) * KT) + (cs >> 1);
                lE[c][j]   = 16384 + rc * 64 + (cb >> 1);
            }
        }
    }

#define STAGEC(c, nxt, k0n)                                              \
    do {                                                                 \
        gload_lds16(((c) < 2 ? Abuf : Bbuf) + goff[c][0] + (k0n),        \
                    &SH[nxt][lE[c][0]]);                                 \
        gload_lds16(((c) < 2 ? Abuf : Bbuf) + goff[c][1] + (k0n),        \
                    &SH[nxt][lE[c][1]]);                                 \
    } while (0)

    // ---- fragment read ELEMENT offsets (swizzled); kk=1 is ^32 elems (^64 bytes)
    int eA[8], eB[4];
#pragma unroll
    for (int m = 0; m < 8; ++m) {
        int row = wm * 128 + m * 16 + (l & 15);
        eA[m] = row * 64 + (((((l >> 4) << 4)) ^ ((row & 7) << 4)) >> 1);
    }
#pragma unroll
    for (int n = 0; n < 4; ++n) {
        int col = wn * 64 + n * 16 + (l & 15);
        eB[n] = 16384 + col * 64 + (((((l >> 4) << 4)) ^ ((col & 7) << 4)) >> 1);
    }

    bf16x8 af[4][2], bfr[4][2];

#define BAR() do { asm volatile("" ::: "memory");                        \
                   __builtin_amdgcn_s_barrier();                         \
                   asm volatile("" ::: "memory"); } while (0)
#define VM(n) asm volatile("s_waitcnt vmcnt(" #n ")" ::: "memory")

#define LDA(qd, buf)                                                     \
    do {                                                                 \
        _Pragma("unroll")                                                \
        for (int m2 = 0; m2 < 4; ++m2) {                                 \
            af[m2][0] = *(const bf16x8*)&SH[buf][eA[(qd)*4 + m2]];       \
            af[m2][1] = *(const bf16x8*)&SH[buf][eA[(qd)*4 + m2] ^ 32];  \
        }                                                                \
    } while (0)

#define LDB(h, buf)                                                      \
    do {                                                                 \
        _Pragma("unroll")                                                \
        for (int n3 = 0; n3 < 2; ++n3) {                                 \
            bfr[(h)*2+n3][0] = *(const bf16x8*)&SH[buf][eB[(h)*2 + n3]]; \
            bfr[(h)*2+n3][1] = *(const bf16x8*)&SH[buf][eB[(h)*2+n3] ^ 32]; \
        }                                                                \
    } while (0)

#define MFMA16(qm, qn)                                                   \
    do {                                                                 \
        __builtin_amdgcn_s_setprio(1);                                   \
        _Pragma("unroll")                                                \
        for (int kk2 = 0; kk2 < 2; ++kk2)                                \
            _Pragma("unroll")                                            \
            for (int m2 = 0; m2 < 4; ++m2)                               \
                _Pragma("unroll")                                        \
                for (int n2 = 0; n2 < 2; ++n2)                           \
                    acc[(qm)*4+m2][(qn)*2+n2] =                          \
                        __builtin_amdgcn_mfma_f32_16x16x32_bf16(         \
                            af[m2][kk2], bfr[(qn)*2+n2][kk2],            \
                            acc[(qm)*4+m2][(qn)*2+n2], 0, 0, 0);         \
        __builtin_amdgcn_s_setprio(0);                                   \
    } while (0)

    // Prologue: stage tile t0 in consumption order; retire c0,c2 (c3,c1 in flight).
    {
        const int k00 = t0 * 64;
        STAGEC(0, 0, k00); STAGEC(2, 0, k00); STAGEC(3, 0, k00); STAGEC(1, 0, k00);
        VM(4);
        BAR();
    }

    // Steady loop: tiles 0..nt-2, each stages tile tt+1 one chunk per phase.
    for (int tt = 0; tt < nt - 1; ++tt) {
        const int cur = tt & 1;
        const int nxt = cur ^ 1;
        const int k0n = (t0 + tt + 1) * 64;
        // ph0: reads c0,c2(t) [covered by prev ph3 vmcnt]; stage c0(t+1); cover c3(t)
        LDA(0, cur); LDB(0, cur);
        STAGEC(0, nxt, k0n);
        VM(4);
        BAR();
        MFMA16(0, 0);
        BAR();
        // ph1: reads c3(t); stage c2(t+1); cover c1(t)
        LDB(1, cur);
        STAGEC(2, nxt, k0n);
        VM(4);
        BAR();
        MFMA16(0, 1);
        BAR();
        // ph2: reads c1(t); stage c3(t+1); no wait
        LDA(1, cur);
        STAGEC(3, nxt, k0n);
        BAR();
        MFMA16(1, 0);
        BAR();
        // ph3: stage c1(t+1); cover c0,c2(t+1) for next tile's ph0 reads
        STAGEC(1, nxt, k0n);
        VM(4);
        BAR();
        MFMA16(1, 1);
        BAR();
    }
    {   // Tail tile (no staging): drain 2 -> 0
        const int cur = (nt - 1) & 1;
        LDA(0, cur); LDB(0, cur);
        VM(2);
        BAR();
        MFMA16(0, 0);
        BAR();
        LDB(1, cur);
        VM(0);
        BAR();
        MFMA16(0, 1);
        BAR();
        LDA(1, cur);
        BAR();
        MFMA16(1, 0);
        BAR();
        MFMA16(1, 1);
    }

    // Split-K partial store (plain f32, no atomics).
    // C/D layout: col = lane&15, row = (lane>>4)*4 + reg  [m89/m91-verified]
    float* pz = part + (size_t)bz * MN;
    const int r0 = bm * 256 + wm * 128 + ((l >> 4) << 2);
    const int c0 = bn * 256 + wn * 64 + (l & 15);
#pragma unroll
    for (int m = 0; m < 8; ++m) {
#pragma unroll
        for (int i = 0; i < 4; ++i) {
            float* prow = pz + (size_t)(r0 + m * 16 + i) * NRES;
#pragma unroll
            for (int n = 0; n < 4; ++n)
                prow[c0 + n * 16] = acc[m][n][i];
        }
    }
#undef STAGEC
#undef BAR
#undef VM
#undef LDA
#undef LDB
#undef MFMA16
}

__global__ __launch_bounds__(256) void epilogue_kernel(
    const float* __restrict__ part, int split, const float* __restrict__ xin,
    const float* __restrict__ Bin, float* __restrict__ out)
{
    size_t id = (size_t)blockIdx.x * 256u + threadIdx.x;   // 1,048,576 units
    size_t e  = id * 4;
    int c = (int)(e & (NRES - 1));
    f32x4 s = *(const f32x4*)(part + e);
    for (int z = 1; z < split; ++z) {
        f32x4 p = *(const f32x4*)(part + (size_t)z * MN + e);
        s += p;
    }
    f32x4 xv = *(const f32x4*)(xin + e);
    f32x4 bv = *(const f32x4*)(Bin + c);
    f32x4 o;
#pragma unroll
    for (int j = 0; j < 4; ++j)
        o[j] = 0.1f * xv[j] + 0.9f * tanhf(s[j] + bv[j]);
    *(f32x4*)(out + e) = o;
}

extern "C" void kernel_launch(void* const* d_in, const int* in_sizes, int n_in,
                              void* d_out, int out_size, void* d_ws, size_t ws_size,
                              hipStream_t stream) {
    (void)in_sizes; (void)n_in; (void)out_size;
    const float* passed     = (const float*)d_in[0];
    const float* lastOutput = (const float*)d_in[1];
    const float* lastPred   = (const float*)d_in[2];
    const float* x          = (const float*)d_in[3];
    const float* prob       = (const float*)d_in[4];
    const float* rand_num   = (const float*)d_in[5];
    const float* W_in       = (const float*)d_in[6];
    const float* W_res      = (const float*)d_in[7];
    const float* W_out      = (const float*)d_in[8];
    const float* B_in       = (const float*)d_in[9];
    float* out = (float*)d_out;

    const size_t AB = (size_t)(NBATCH + NRES) * KT * 2;   // 47,841,280 B
    __bf16* Abuf = (__bf16*)d_ws;
    __bf16* Bbuf = (__bf16*)((char*)d_ws + (size_t)NBATCH * KT * 2);
    float*  part = (float*)((char*)d_ws + AB);

    // ws-guarded split-K factor (deterministic: ws_size fixed per session)
    int split = 1;
    if (ws_size >= AB + 4 * MN * sizeof(float))      split = 4;
    else if (ws_size >= AB + 2 * MN * sizeof(float)) split = 2;

    pack_A4<<<(NBATCH * KQ) / 256, 256, 0, stream>>>(
        x, passed, lastOutput, lastPred, prob, rand_num, Abuf);
    pack_B4<<<(NRES * KQ) / 256, 256, 0, stream>>>(
        W_res, W_in, W_out, Bbuf);

    dim3 grid(NRES / 256, NBATCH / 256, split);
    gemm_kernel<<<grid, 512, 0, stream>>>(Abuf, Bbuf, part, split);

    epilogue_kernel<<<4096, 256, 0, stream>>>(part, split, x, B_in, out);
}